// Round 2
// baseline (448.666 us; speedup 1.0000x reference)
//
#include <hip/hip_runtime.h>

// WordAttention: B=8, S=2048, D_IN=D_H=512, fp32 in/out.
// Precision strategy: double-bf16 (hi+lo) emulation through the Q/K chain
// (x, Wq/Wk, Q, K all split; 3-term MFMA for projections and scores) so the
// logits are ~fp32-exact. V / P / PV stay single-bf16 (sub-threshold error).

typedef __attribute__((ext_vector_type(8))) short bf16x8;
typedef __attribute__((ext_vector_type(4))) float f32x4;

__device__ __forceinline__ unsigned short f2bf(float f) {
  unsigned int u = __float_as_uint(f);
  unsigned int r = (u + 0x7fffu + ((u >> 16) & 1u)) >> 16;
  return (unsigned short)r;
}
__device__ __forceinline__ float bf2f(unsigned short h) {
  return __uint_as_float(((unsigned int)h) << 16);
}

__device__ __forceinline__ void load_lds16(const void* g, void* l) {
  __builtin_amdgcn_global_load_lds(
      (const __attribute__((address_space(1))) unsigned int*)g,
      (__attribute__((address_space(3))) unsigned int*)l, 16, 0, 0);
}

// ---- x fp32 -> bf16 hi + lo (one float4 per thread) ----
__global__ __launch_bounds__(256) void convx_split_kernel(
    const float* __restrict__ x, unsigned short* __restrict__ xhi,
    unsigned short* __restrict__ xlo) {
  int i = blockIdx.x * 256 + threadIdx.x;
  float4 v = ((const float4*)x)[i];
  float f[4] = {v.x, v.y, v.z, v.w};
  union { unsigned short h[4]; short4 s4; } uh, ul;
#pragma unroll
  for (int k = 0; k < 4; k++) {
    unsigned short h = f2bf(f[k]);
    uh.h[k] = h;
    ul.h[k] = f2bf(f[k] - bf2f(h));
  }
  ((short4*)xhi)[i] = uh.s4;
  ((short4*)xlo)[i] = ul.s4;
}

// ---- W [d][h] fp32 -> Wt [h][d] bf16 hi + lo (512x512) ----
__global__ __launch_bounds__(256) void convw_split_kernel(
    const float* __restrict__ W, unsigned short* __restrict__ Wth,
    unsigned short* __restrict__ Wtl) {
  __shared__ float tile[32][33];
  int tx = threadIdx.x, ty = threadIdx.y;  // 32 x 8
  int h0 = blockIdx.x * 32, d0 = blockIdx.y * 32;
  for (int i = ty; i < 32; i += 8) tile[i][tx] = W[(long)(d0 + i) * 512 + h0 + tx];
  __syncthreads();
  for (int i = ty; i < 32; i += 8) {
    float f = tile[tx][i];
    unsigned short h = f2bf(f);
    long idx = (long)(h0 + i) * 512 + d0 + tx;
    Wth[idx] = h;
    Wtl[idx] = f2bf(f - bf2f(h));
  }
}

// ---- V [b][s][d] bf16 -> VT [b][d][s] bf16 ----
__global__ __launch_bounds__(256) void transv_kernel(const unsigned short* __restrict__ V,
                                                     unsigned short* __restrict__ VT) {
  __shared__ unsigned short tile[64][65];
  int z = blockIdx.z;
  const unsigned short* src = V + (long)z * 2048 * 512;
  unsigned short* dst = VT + (long)z * 512 * 2048;
  int s0 = blockIdx.x * 64, d0 = blockIdx.y * 64;
  int tx = threadIdx.x, ty = threadIdx.y;  // 64 x 4
  for (int i = ty; i < 64; i += 4) tile[i][tx] = src[(long)(s0 + i) * 512 + d0 + tx];
  __syncthreads();
  for (int i = ty; i < 64; i += 4) dst[(long)(d0 + i) * 2048 + s0 + tx] = tile[tx][i];
}

// ---- plain 128x128-tile GEMM, C = A * Bt^T (+bias). 16x16x32 bf16 MFMA. ----
template <bool OUT_BF16, bool BIAS>
__global__ __launch_bounds__(256) void gemm_bt_kernel(
    const unsigned short* __restrict__ A, int lda, long long sA,
    const unsigned short* __restrict__ Bt, int ldb, long long sB,
    void* __restrict__ Cout, int ldc, long long sC,
    const float* __restrict__ bias, int K) {
  __shared__ alignas(16) unsigned short As[128 * 32];
  __shared__ alignas(16) unsigned short Bs[128 * 32];
  const int t = threadIdx.x;
  const long long bm = (long long)blockIdx.x * 128;
  const long long bn = (long long)blockIdx.y * 128;
  const unsigned short* Ab = A + (long long)blockIdx.z * sA;
  const unsigned short* Bb = Bt + (long long)blockIdx.z * sB;

  const int ar = t >> 2;        // row 0..63 within 64-row staging half
  const int ac = (t & 3) * 8;   // k-col start (16 B)

  f32x4 acc[4][4];
#pragma unroll
  for (int i = 0; i < 4; i++)
#pragma unroll
    for (int j = 0; j < 4; j++) acc[i][j] = {0.f, 0.f, 0.f, 0.f};

  const int lane = t & 63;
  const int wave = t >> 6;
  const int wm = (wave & 1) * 64;
  const int wn = (wave >> 1) * 64;
  const int fm = lane & 15;
  const int k8 = (lane >> 4) * 8;

  for (int kt = 0; kt < K; kt += 32) {
#pragma unroll
    for (int r = 0; r < 2; r++)
      load_lds16(Ab + (bm + r * 64 + ar) * lda + kt + ac, &As[r * 2048 + t * 8]);
#pragma unroll
    for (int r = 0; r < 2; r++)
      load_lds16(Bb + (bn + r * 64 + ar) * ldb + kt + ac, &Bs[r * 2048 + t * 8]);
    __syncthreads();

    bf16x8 af[4], bfr[4];
#pragma unroll
    for (int i = 0; i < 4; i++)
      af[i] = *(const bf16x8*)&As[(wm + i * 16 + fm) * 32 + k8];
#pragma unroll
    for (int j = 0; j < 4; j++)
      bfr[j] = *(const bf16x8*)&Bs[(wn + j * 16 + fm) * 32 + k8];
#pragma unroll
    for (int i = 0; i < 4; i++)
#pragma unroll
      for (int j = 0; j < 4; j++)
        acc[i][j] = __builtin_amdgcn_mfma_f32_16x16x32_bf16(af[i], bfr[j], acc[i][j], 0, 0, 0);
    __syncthreads();
  }

  float* Cf = (float*)Cout;
  unsigned short* Cb = (unsigned short*)Cout;
  const long long cz = (long long)blockIdx.z * sC;
  const int crow = (lane >> 4) * 4;  // C/D: col=lane&15, row=(lane>>4)*4+reg
  const int ccol = lane & 15;
#pragma unroll
  for (int j = 0; j < 4; j++) {
    const long long col = bn + wn + j * 16 + ccol;
    float bv = 0.0f;
    if (BIAS) bv = bias[col];
#pragma unroll
    for (int i = 0; i < 4; i++) {
      const long long row0 = bm + wm + i * 16 + crow;
#pragma unroll
      for (int r = 0; r < 4; r++) {
        float v = acc[i][j][r] + bv;
        long long idx = cz + (row0 + r) * ldc + col;
        if (OUT_BF16) Cb[idx] = f2bf(v);
        else          Cf[idx] = v;
      }
    }
  }
}

// ---- split (double-bf16) GEMM: C = (Ahi+Alo) * (Bhi+Blo)^T, dropping lo*lo.
//      OUT_MODE 0: fp32 C into C0.  OUT_MODE 1: split bf16 (C0=hi, C1=lo), +bias.
template <int OUT_MODE, bool BIAS>
__global__ __launch_bounds__(256) void gemm3_kernel(
    const unsigned short* __restrict__ Ahi, const unsigned short* __restrict__ Alo,
    int lda, long long sA,
    const unsigned short* __restrict__ Bhi, const unsigned short* __restrict__ Blo,
    int ldb, long long sB,
    void* __restrict__ C0, void* __restrict__ C1, int ldc, long long sC,
    const float* __restrict__ bias, int K) {
  __shared__ alignas(16) unsigned short As[2][128 * 32];  // [hi/lo]
  __shared__ alignas(16) unsigned short Bs[2][128 * 32];
  const int t = threadIdx.x;
  const long long bm = (long long)blockIdx.x * 128;
  const long long bn = (long long)blockIdx.y * 128;
  const unsigned short* Ah = Ahi + (long long)blockIdx.z * sA;
  const unsigned short* Al = Alo + (long long)blockIdx.z * sA;
  const unsigned short* Bh = Bhi + (long long)blockIdx.z * sB;
  const unsigned short* Bl = Blo + (long long)blockIdx.z * sB;

  const int ar = t >> 2;
  const int ac = (t & 3) * 8;

  f32x4 acc[4][4];
#pragma unroll
  for (int i = 0; i < 4; i++)
#pragma unroll
    for (int j = 0; j < 4; j++) acc[i][j] = {0.f, 0.f, 0.f, 0.f};

  const int lane = t & 63;
  const int wave = t >> 6;
  const int wm = (wave & 1) * 64;
  const int wn = (wave >> 1) * 64;
  const int fm = lane & 15;
  const int k8 = (lane >> 4) * 8;

  for (int kt = 0; kt < K; kt += 32) {
#pragma unroll
    for (int r = 0; r < 2; r++) {
      long long arow = (bm + r * 64 + ar) * lda + kt + ac;
      load_lds16(Ah + arow, &As[0][r * 2048 + t * 8]);
      load_lds16(Al + arow, &As[1][r * 2048 + t * 8]);
      long long brow = (bn + r * 64 + ar) * ldb + kt + ac;
      load_lds16(Bh + brow, &Bs[0][r * 2048 + t * 8]);
      load_lds16(Bl + brow, &Bs[1][r * 2048 + t * 8]);
    }
    __syncthreads();

    bf16x8 afh[4], afl[4], bfh[4], bfl[4];
#pragma unroll
    for (int i = 0; i < 4; i++) {
      afh[i] = *(const bf16x8*)&As[0][(wm + i * 16 + fm) * 32 + k8];
      afl[i] = *(const bf16x8*)&As[1][(wm + i * 16 + fm) * 32 + k8];
    }
#pragma unroll
    for (int j = 0; j < 4; j++) {
      bfh[j] = *(const bf16x8*)&Bs[0][(wn + j * 16 + fm) * 32 + k8];
      bfl[j] = *(const bf16x8*)&Bs[1][(wn + j * 16 + fm) * 32 + k8];
    }
#pragma unroll
    for (int i = 0; i < 4; i++)
#pragma unroll
      for (int j = 0; j < 4; j++) {
        acc[i][j] = __builtin_amdgcn_mfma_f32_16x16x32_bf16(afh[i], bfh[j], acc[i][j], 0, 0, 0);
        acc[i][j] = __builtin_amdgcn_mfma_f32_16x16x32_bf16(afh[i], bfl[j], acc[i][j], 0, 0, 0);
        acc[i][j] = __builtin_amdgcn_mfma_f32_16x16x32_bf16(afl[i], bfh[j], acc[i][j], 0, 0, 0);
      }
    __syncthreads();
  }

  float* Cf = (float*)C0;
  unsigned short* Chb = (unsigned short*)C0;
  unsigned short* Clb = (unsigned short*)C1;
  const long long cz = (long long)blockIdx.z * sC;
  const int crow = (lane >> 4) * 4;
  const int ccol = lane & 15;
#pragma unroll
  for (int j = 0; j < 4; j++) {
    const long long col = bn + wn + j * 16 + ccol;
    float bv = 0.0f;
    if (BIAS) bv = bias[col];
#pragma unroll
    for (int i = 0; i < 4; i++) {
      const long long row0 = bm + wm + i * 16 + crow;
#pragma unroll
      for (int r = 0; r < 4; r++) {
        float v = acc[i][j][r] + bv;
        long long idx = cz + (row0 + r) * ldc + col;
        if (OUT_MODE == 0) {
          Cf[idx] = v;
        } else {
          unsigned short h = f2bf(v);
          Chb[idx] = h;
          Clb[idx] = f2bf(v - bf2f(h));
        }
      }
    }
  }
}

// ---- row softmax over 2048 fp32 logits; writes bf16 P in place (row head) ----
__global__ __launch_bounds__(256) void softmax_kernel(float* __restrict__ S) {
  float* Srow = S + (long long)blockIdx.x * 2048;
  const int t = threadIdx.x;
  float4 v0 = ((const float4*)Srow)[t * 2];
  float4 v1 = ((const float4*)Srow)[t * 2 + 1];
  float m = fmaxf(fmaxf(fmaxf(v0.x, v0.y), fmaxf(v0.z, v0.w)),
                  fmaxf(fmaxf(v1.x, v1.y), fmaxf(v1.z, v1.w)));
#pragma unroll
  for (int off = 32; off > 0; off >>= 1) m = fmaxf(m, __shfl_xor(m, off));
  __shared__ float redm[4];
  __shared__ float reds[4];
  const int wave = t >> 6, lane = t & 63;
  if (lane == 0) redm[wave] = m;
  __syncthreads();
  m = fmaxf(fmaxf(redm[0], redm[1]), fmaxf(redm[2], redm[3]));
  float e[8];
  e[0] = __expf(v0.x - m); e[1] = __expf(v0.y - m);
  e[2] = __expf(v0.z - m); e[3] = __expf(v0.w - m);
  e[4] = __expf(v1.x - m); e[5] = __expf(v1.y - m);
  e[6] = __expf(v1.z - m); e[7] = __expf(v1.w - m);
  float s = 0.f;
#pragma unroll
  for (int k = 0; k < 8; k++) s += e[k];
#pragma unroll
  for (int off = 32; off > 0; off >>= 1) s += __shfl_xor(s, off);
  if (lane == 0) reds[wave] = s;
  __syncthreads();
  s = reds[0] + reds[1] + reds[2] + reds[3];
  float inv = 1.0f / s;
  union { unsigned short h[8]; int4 v; } u;
#pragma unroll
  for (int k = 0; k < 8; k++) u.h[k] = f2bf(e[k] * inv);
  ((int4*)Srow)[t] = u.v;  // bf16 row occupies first half of the fp32 row
}

extern "C" void kernel_launch(void* const* d_in, const int* in_sizes, int n_in,
                              void* d_out, int out_size, void* d_ws, size_t ws_size,
                              hipStream_t stream) {
  const float* x  = (const float*)d_in[0];
  const float* Wq = (const float*)d_in[1];
  const float* bq = (const float*)d_in[2];
  const float* Wk = (const float*)d_in[3];
  const float* bk = (const float*)d_in[4];
  const float* Wv = (const float*)d_in[5];
  const float* bv = (const float*)d_in[6];
  float* out = (float*)d_out;

  const size_t SZ = (size_t)16384 * 512 * 2;   // 16.78 MB (one bf16 [16384,512])
  const size_t WSZ = (size_t)3 * 512 * 512 * 2;
  const size_t S1 = (size_t)2048 * 2048 * 4;   // one batch of fp32 scores

  char* p = (char*)d_ws;
  unsigned short* xhi = (unsigned short*)p; p += SZ;
  unsigned short* xlo = (unsigned short*)p; p += SZ;
  unsigned short* Wth = (unsigned short*)p; p += WSZ;
  unsigned short* Wtl = (unsigned short*)p; p += WSZ;
  unsigned short* Qhi = (unsigned short*)p; p += SZ;
  unsigned short* Qlo = (unsigned short*)p; p += SZ;
  unsigned short* Khi = (unsigned short*)p; p += SZ;
  unsigned short* Klo = (unsigned short*)p; p += SZ;
  unsigned short* V   = (unsigned short*)p; p += SZ;
  unsigned short* VT  = (unsigned short*)p; p += SZ;
  size_t fixed = (size_t)(p - (char*)d_ws);

  float* S;
  int NB;
  if (ws_size >= fixed + 8 * S1)      { NB = 8; S = (float*)p; }
  else if (ws_size >= fixed + 4 * S1) { NB = 4; S = (float*)p; }
  else if (ws_size >= fixed + 2 * S1) { NB = 2; S = (float*)p; }
  else if (ws_size >= fixed)          { NB = 2; S = (float*)xhi; }  // x dead by then
  else { VT = xlo; NB = 1; S = (float*)xhi; }                        // ultra-tight

  // 1) conversions (split x / W)
  convx_split_kernel<<<8192, 256, 0, stream>>>(x, xhi, xlo);
  dim3 wb(32, 8);
  convw_split_kernel<<<dim3(16, 16), wb, 0, stream>>>(Wq, Wth, Wtl);
  convw_split_kernel<<<dim3(16, 16), wb, 0, stream>>>(Wk, Wth + 512 * 512, Wtl + 512 * 512);
  convw_split_kernel<<<dim3(16, 16), wb, 0, stream>>>(Wv, Wth + 2 * 512 * 512, Wtl + 2 * 512 * 512);

  // 2) projections: Q,K in double-bf16; V single-bf16
  gemm3_kernel<1, true><<<dim3(128, 4, 1), 256, 0, stream>>>(
      xhi, xlo, 512, 0, Wth, Wtl, 512, 0, Qhi, Qlo, 512, 0, bq, 512);
  gemm3_kernel<1, true><<<dim3(128, 4, 1), 256, 0, stream>>>(
      xhi, xlo, 512, 0, Wth + 512 * 512, Wtl + 512 * 512, 512, 0, Khi, Klo, 512, 0, bk, 512);
  gemm_bt_kernel<true, true><<<dim3(128, 4, 1), 256, 0, stream>>>(
      xhi, 512, 0, Wth + 2 * 512 * 512, 512, 0, V, 512, 0, bv, 512);

  // 3) V transpose per batch
  transv_kernel<<<dim3(32, 8, 8), dim3(64, 4), 0, stream>>>(V, VT);

  // 4) attention, chunked over batches
  for (int b0 = 0; b0 < 8; b0 += NB) {
    // scores (double-bf16): S[b][q][k] = (Q[b]) (K[b])^T, fp32 out
    gemm3_kernel<0, false><<<dim3(16, 16, NB), 256, 0, stream>>>(
        Qhi + (size_t)b0 * 1048576, Qlo + (size_t)b0 * 1048576, 512, 1048576LL,
        Khi + (size_t)b0 * 1048576, Klo + (size_t)b0 * 1048576, 512, 1048576LL,
        S, nullptr, 2048, 4194304LL, nullptr, 512);
    // softmax rows -> bf16 P in place
    softmax_kernel<<<NB * 2048, 256, 0, stream>>>(S);
    // out[b] = P[b] * V[b]
    gemm_bt_kernel<false, false><<<dim3(16, 4, NB), 256, 0, stream>>>(
        (const unsigned short*)S, 4096, 8388608LL,
        VT + (size_t)b0 * 1048576, 2048, 1048576LL,
        out + (size_t)b0 * 1048576, 512, 1048576LL, nullptr, 2048);
  }
}

// Round 3
// 376.322 us; speedup vs baseline: 1.1922x; 1.1922x over previous
//
#include <hip/hip_runtime.h>

// WordAttention: B=8, S=2048, D_IN=D_H=512, fp32 in/out.
// Double-bf16 (hi+lo) through the Q/K chain; V/P/PV single-bf16.
// R3: 7 dispatches: convx, convw(x3 fused), QK-proj(fused), V-proj(->VT direct),
//     scores, softmax(packed P), PV.

typedef __attribute__((ext_vector_type(8))) short bf16x8;
typedef __attribute__((ext_vector_type(4))) float f32x4;

__device__ __forceinline__ unsigned short f2bf(float f) {
  unsigned int u = __float_as_uint(f);
  unsigned int r = (u + 0x7fffu + ((u >> 16) & 1u)) >> 16;
  return (unsigned short)r;
}
__device__ __forceinline__ float bf2f(unsigned short h) {
  return __uint_as_float(((unsigned int)h) << 16);
}

__device__ __forceinline__ void load_lds16(const void* g, void* l) {
  __builtin_amdgcn_global_load_lds(
      (const __attribute__((address_space(1))) unsigned int*)g,
      (__attribute__((address_space(3))) unsigned int*)l, 16, 0, 0);
}

// ---- x fp32 -> bf16 hi + lo ----
__global__ __launch_bounds__(256) void convx_split_kernel(
    const float* __restrict__ x, unsigned short* __restrict__ xhi,
    unsigned short* __restrict__ xlo) {
  int i = blockIdx.x * 256 + threadIdx.x;
  float4 v = ((const float4*)x)[i];
  float f[4] = {v.x, v.y, v.z, v.w};
  union { unsigned short h[4]; short4 s4; } uh, ul;
#pragma unroll
  for (int k = 0; k < 4; k++) {
    unsigned short h = f2bf(f[k]);
    uh.h[k] = h;
    ul.h[k] = f2bf(f[k] - bf2f(h));
  }
  ((short4*)xhi)[i] = uh.s4;
  ((short4*)xlo)[i] = ul.s4;
}

// ---- W [d][h] fp32 -> Wt [h][d] bf16 hi + lo; z selects which W ----
__global__ __launch_bounds__(256) void convw_split_kernel(
    const float* __restrict__ W0, const float* __restrict__ W1,
    const float* __restrict__ W2, unsigned short* __restrict__ Wth,
    unsigned short* __restrict__ Wtl) {
  const float* W = (blockIdx.z == 0) ? W0 : (blockIdx.z == 1) ? W1 : W2;
  unsigned short* th = Wth + (size_t)blockIdx.z * 512 * 512;
  unsigned short* tl = Wtl + (size_t)blockIdx.z * 512 * 512;
  __shared__ float tile[32][33];
  int tx = threadIdx.x, ty = threadIdx.y;  // 32 x 8
  int h0 = blockIdx.x * 32, d0 = blockIdx.y * 32;
  for (int i = ty; i < 32; i += 8) tile[i][tx] = W[(long)(d0 + i) * 512 + h0 + tx];
  __syncthreads();
  for (int i = ty; i < 32; i += 8) {
    float f = tile[tx][i];
    unsigned short h = f2bf(f);
    long idx = (long)(h0 + i) * 512 + d0 + tx;
    th[idx] = h;
    tl[idx] = f2bf(f - bf2f(h));
  }
}

// ---- plain 128x128-tile GEMM, C = A * Bt^T (+bias). 16x16x32 bf16 MFMA.
//      OUT_KIND: 0 = fp32 C, 1 = bf16 C, 2 = bf16 transposed into VT[b][h][s]
template <int OUT_KIND, bool BIAS>
__global__ __launch_bounds__(256) void gemm_bt_kernel(
    const unsigned short* __restrict__ A, int lda, long long sA,
    const unsigned short* __restrict__ Bt, int ldb, long long sB,
    void* __restrict__ Cout, int ldc, long long sC,
    const float* __restrict__ bias, int K) {
  __shared__ alignas(16) unsigned short As[128 * 32];
  __shared__ alignas(16) unsigned short Bs[128 * 32];
  const int t = threadIdx.x;
  const long long bm = (long long)blockIdx.x * 128;
  const long long bn = (long long)blockIdx.y * 128;
  const unsigned short* Ab = A + (long long)blockIdx.z * sA;
  const unsigned short* Bb = Bt + (long long)blockIdx.z * sB;

  const int ar = t >> 2;        // row 0..63 within 64-row staging half
  const int ac = (t & 3) * 8;   // k-col start (16 B)

  f32x4 acc[4][4];
#pragma unroll
  for (int i = 0; i < 4; i++)
#pragma unroll
    for (int j = 0; j < 4; j++) acc[i][j] = {0.f, 0.f, 0.f, 0.f};

  const int lane = t & 63;
  const int wave = t >> 6;
  const int wm = (wave & 1) * 64;
  const int wn = (wave >> 1) * 64;
  const int fm = lane & 15;
  const int k8 = (lane >> 4) * 8;

  for (int kt = 0; kt < K; kt += 32) {
#pragma unroll
    for (int r = 0; r < 2; r++)
      load_lds16(Ab + (bm + r * 64 + ar) * lda + kt + ac, &As[r * 2048 + t * 8]);
#pragma unroll
    for (int r = 0; r < 2; r++)
      load_lds16(Bb + (bn + r * 64 + ar) * ldb + kt + ac, &Bs[r * 2048 + t * 8]);
    __syncthreads();

    bf16x8 af[4], bfr[4];
#pragma unroll
    for (int i = 0; i < 4; i++)
      af[i] = *(const bf16x8*)&As[(wm + i * 16 + fm) * 32 + k8];
#pragma unroll
    for (int j = 0; j < 4; j++)
      bfr[j] = *(const bf16x8*)&Bs[(wn + j * 16 + fm) * 32 + k8];
#pragma unroll
    for (int i = 0; i < 4; i++)
#pragma unroll
      for (int j = 0; j < 4; j++)
        acc[i][j] = __builtin_amdgcn_mfma_f32_16x16x32_bf16(af[i], bfr[j], acc[i][j], 0, 0, 0);
    __syncthreads();
  }

  float* Cf = (float*)Cout;
  unsigned short* Cb = (unsigned short*)Cout;
  const long long cz = (long long)blockIdx.z * sC;
  const int crow = (lane >> 4) * 4;  // C/D: col=lane&15, row=(lane>>4)*4+reg
  const int ccol = lane & 15;
#pragma unroll
  for (int j = 0; j < 4; j++) {
    const long long col = bn + wn + j * 16 + ccol;
    float bv = 0.0f;
    if (BIAS) bv = bias[col];
#pragma unroll
    for (int i = 0; i < 4; i++) {
      const long long row0 = bm + wm + i * 16 + crow;
      if (OUT_KIND == 2) {
        // VT[b][col][s], s = row0..row0+3 consecutive within one batch
        const long long b = row0 >> 11;
        const long long s = row0 & 2047;
        union { unsigned short h[4]; short4 s4; } u;
#pragma unroll
        for (int r = 0; r < 4; r++) u.h[r] = f2bf(acc[i][j][r] + bv);
        *(short4*)(Cb + (b * 512 + col) * 2048 + s) = u.s4;
      } else {
#pragma unroll
        for (int r = 0; r < 4; r++) {
          float v = acc[i][j][r] + bv;
          long long idx = cz + (row0 + r) * ldc + col;
          if (OUT_KIND == 1) Cb[idx] = f2bf(v);
          else               Cf[idx] = v;
        }
      }
    }
  }
}

// ---- split (double-bf16) GEMM: C = (Ahi+Alo)*(Bhi+Blo)^T, dropping lo*lo.
//      OUT_MODE 0: fp32 C into C0.
//      OUT_MODE 1: split bf16 (C0=hi, C1=lo); bias = bias0 for col<512 else bias1.
template <int OUT_MODE, bool BIAS>
__global__ __launch_bounds__(256) void gemm3_kernel(
    const unsigned short* __restrict__ Ahi, const unsigned short* __restrict__ Alo,
    int lda, long long sA,
    const unsigned short* __restrict__ Bhi, const unsigned short* __restrict__ Blo,
    int ldb, long long sB,
    void* __restrict__ C0, void* __restrict__ C1, int ldc, long long sC,
    const float* __restrict__ bias0, const float* __restrict__ bias1, int K) {
  __shared__ alignas(16) unsigned short As[2][128 * 32];  // [hi/lo]
  __shared__ alignas(16) unsigned short Bs[2][128 * 32];
  const int t = threadIdx.x;
  const long long bm = (long long)blockIdx.x * 128;
  const long long bn = (long long)blockIdx.y * 128;
  const unsigned short* Ah = Ahi + (long long)blockIdx.z * sA;
  const unsigned short* Al = Alo + (long long)blockIdx.z * sA;
  const unsigned short* Bh = Bhi + (long long)blockIdx.z * sB;
  const unsigned short* Bl = Blo + (long long)blockIdx.z * sB;

  const int ar = t >> 2;
  const int ac = (t & 3) * 8;

  f32x4 acc[4][4];
#pragma unroll
  for (int i = 0; i < 4; i++)
#pragma unroll
    for (int j = 0; j < 4; j++) acc[i][j] = {0.f, 0.f, 0.f, 0.f};

  const int lane = t & 63;
  const int wave = t >> 6;
  const int wm = (wave & 1) * 64;
  const int wn = (wave >> 1) * 64;
  const int fm = lane & 15;
  const int k8 = (lane >> 4) * 8;

  for (int kt = 0; kt < K; kt += 32) {
#pragma unroll
    for (int r = 0; r < 2; r++) {
      long long arow = (bm + r * 64 + ar) * lda + kt + ac;
      load_lds16(Ah + arow, &As[0][r * 2048 + t * 8]);
      load_lds16(Al + arow, &As[1][r * 2048 + t * 8]);
      long long brow = (bn + r * 64 + ar) * ldb + kt + ac;
      load_lds16(Bh + brow, &Bs[0][r * 2048 + t * 8]);
      load_lds16(Bl + brow, &Bs[1][r * 2048 + t * 8]);
    }
    __syncthreads();

    bf16x8 afh[4], afl[4], bfh[4], bfl[4];
#pragma unroll
    for (int i = 0; i < 4; i++) {
      afh[i] = *(const bf16x8*)&As[0][(wm + i * 16 + fm) * 32 + k8];
      afl[i] = *(const bf16x8*)&As[1][(wm + i * 16 + fm) * 32 + k8];
    }
#pragma unroll
    for (int j = 0; j < 4; j++) {
      bfh[j] = *(const bf16x8*)&Bs[0][(wn + j * 16 + fm) * 32 + k8];
      bfl[j] = *(const bf16x8*)&Bs[1][(wn + j * 16 + fm) * 32 + k8];
    }
#pragma unroll
    for (int i = 0; i < 4; i++)
#pragma unroll
      for (int j = 0; j < 4; j++) {
        acc[i][j] = __builtin_amdgcn_mfma_f32_16x16x32_bf16(afh[i], bfh[j], acc[i][j], 0, 0, 0);
        acc[i][j] = __builtin_amdgcn_mfma_f32_16x16x32_bf16(afh[i], bfl[j], acc[i][j], 0, 0, 0);
        acc[i][j] = __builtin_amdgcn_mfma_f32_16x16x32_bf16(afl[i], bfh[j], acc[i][j], 0, 0, 0);
      }
    __syncthreads();
  }

  float* Cf = (float*)C0;
  unsigned short* Chb = (unsigned short*)C0;
  unsigned short* Clb = (unsigned short*)C1;
  const long long cz = (long long)blockIdx.z * sC;
  const int crow = (lane >> 4) * 4;
  const int ccol = lane & 15;
#pragma unroll
  for (int j = 0; j < 4; j++) {
    const long long col = bn + wn + j * 16 + ccol;
    float bv = 0.0f;
    if (BIAS) bv = (col < 512) ? bias0[col] : bias1[col - 512];
#pragma unroll
    for (int i = 0; i < 4; i++) {
      const long long row0 = bm + wm + i * 16 + crow;
#pragma unroll
      for (int r = 0; r < 4; r++) {
        float v = acc[i][j][r] + bv;
        long long idx = cz + (row0 + r) * ldc + col;
        if (OUT_MODE == 0) {
          Cf[idx] = v;
        } else {
          unsigned short h = f2bf(v);
          Chb[idx] = h;
          Clb[idx] = f2bf(v - bf2f(h));
        }
      }
    }
  }
}

// ---- row softmax over 2048 fp32 logits -> bf16 P (pstride shorts per row) ----
__global__ __launch_bounds__(256) void softmax_kernel(const float* __restrict__ S,
                                                      unsigned short* __restrict__ P,
                                                      int pstride) {
  const float* Srow = S + (long long)blockIdx.x * 2048;
  unsigned short* Prow = P + (long long)blockIdx.x * pstride;
  const int t = threadIdx.x;
  float4 v0 = ((const float4*)Srow)[t * 2];
  float4 v1 = ((const float4*)Srow)[t * 2 + 1];
  float m = fmaxf(fmaxf(fmaxf(v0.x, v0.y), fmaxf(v0.z, v0.w)),
                  fmaxf(fmaxf(v1.x, v1.y), fmaxf(v1.z, v1.w)));
#pragma unroll
  for (int off = 32; off > 0; off >>= 1) m = fmaxf(m, __shfl_xor(m, off));
  __shared__ float redm[4];
  __shared__ float reds[4];
  const int wave = t >> 6, lane = t & 63;
  if (lane == 0) redm[wave] = m;
  __syncthreads();  // fences the global reads above from the (aliasing) writes below
  m = fmaxf(fmaxf(redm[0], redm[1]), fmaxf(redm[2], redm[3]));
  float e[8];
  e[0] = __expf(v0.x - m); e[1] = __expf(v0.y - m);
  e[2] = __expf(v0.z - m); e[3] = __expf(v0.w - m);
  e[4] = __expf(v1.x - m); e[5] = __expf(v1.y - m);
  e[6] = __expf(v1.z - m); e[7] = __expf(v1.w - m);
  float s = 0.f;
#pragma unroll
  for (int k = 0; k < 8; k++) s += e[k];
#pragma unroll
  for (int off = 32; off > 0; off >>= 1) s += __shfl_xor(s, off);
  if (lane == 0) reds[wave] = s;
  __syncthreads();
  s = reds[0] + reds[1] + reds[2] + reds[3];
  float inv = 1.0f / s;
  union { unsigned short h[8]; int4 v; } u;
#pragma unroll
  for (int k = 0; k < 8; k++) u.h[k] = f2bf(e[k] * inv);
  ((int4*)Prow)[t] = u.v;
}

extern "C" void kernel_launch(void* const* d_in, const int* in_sizes, int n_in,
                              void* d_out, int out_size, void* d_ws, size_t ws_size,
                              hipStream_t stream) {
  const float* x  = (const float*)d_in[0];
  const float* Wq = (const float*)d_in[1];
  const float* bq = (const float*)d_in[2];
  const float* Wk = (const float*)d_in[3];
  const float* bk = (const float*)d_in[4];
  const float* Wv = (const float*)d_in[5];
  const float* bv = (const float*)d_in[6];
  float* out = (float*)d_out;

  const size_t SZ  = (size_t)16384 * 512 * 2;  // 16.78 MB (bf16 [16384,512])
  const size_t WSZ = (size_t)3 * 512 * 512 * 2;
  const size_t S1  = (size_t)2048 * 2048 * 4;  // one batch of fp32 scores

  char* p = (char*)d_ws;
  unsigned short* xhi  = (unsigned short*)p; p += SZ;
  unsigned short* xlo  = (unsigned short*)p; p += SZ;
  unsigned short* Wth  = (unsigned short*)p; p += WSZ;
  unsigned short* Wtl  = (unsigned short*)p; p += WSZ;
  unsigned short* QKhi = (unsigned short*)p; p += 2 * SZ;  // [16384][1024]: Q|K
  unsigned short* QKlo = (unsigned short*)p; p += 2 * SZ;
  unsigned short* VT   = (unsigned short*)p; p += SZ;      // [b][512][2048]
  size_t fixed = (size_t)(p - (char*)d_ws);

  float* S;
  int NB;
  bool packedP;
  if (ws_size >= fixed + 8 * S1)      { NB = 8; S = (float*)p; packedP = true; }
  else if (ws_size >= fixed + 4 * S1) { NB = 4; S = (float*)p; packedP = false; }
  else if (ws_size >= fixed + 2 * S1) { NB = 2; S = (float*)p; packedP = false; }
  else if (ws_size >= fixed)          { NB = 2; S = (float*)xhi; packedP = false; }
  else { VT = xlo; NB = 1; S = (float*)xhi; packedP = false; }
  unsigned short* Pk = QKhi;  // packed P aliases dead Q/K (67 MB, only if NB==8)

  // 1) conversions
  convx_split_kernel<<<8192, 256, 0, stream>>>(x, xhi, xlo);
  convw_split_kernel<<<dim3(16, 16, 3), dim3(32, 8), 0, stream>>>(Wq, Wk, Wv, Wth, Wtl);

  // 2) projections: fused Q|K double-bf16 (N=1024); V single-bf16 -> VT direct
  gemm3_kernel<1, true><<<dim3(128, 8, 1), 256, 0, stream>>>(
      xhi, xlo, 512, 0, Wth, Wtl, 512, 0, QKhi, QKlo, 1024, 0, bq, bk, 512);
  gemm_bt_kernel<2, true><<<dim3(128, 4, 1), 256, 0, stream>>>(
      xhi, 512, 0, Wth + 2 * 512 * 512, 512, 0, VT, 0, 0, bv, 512);

  // 3) attention, chunked over batches
  for (int b0 = 0; b0 < 8; b0 += NB) {
    // scores (double-bf16): S[b][q][k] = Q[b] K[b]^T, fp32
    gemm3_kernel<0, false><<<dim3(16, 16, NB), 256, 0, stream>>>(
        QKhi + (size_t)b0 * 2097152, QKlo + (size_t)b0 * 2097152, 1024, 2097152LL,
        QKhi + 512 + (size_t)b0 * 2097152, QKlo + 512 + (size_t)b0 * 2097152, 1024, 2097152LL,
        S, nullptr, 2048, 4194304LL, nullptr, nullptr, 512);
    // softmax rows -> bf16 P (packed when NB==8, else in place over S)
    unsigned short* Pdst = packedP ? Pk : (unsigned short*)S;
    int pstride = packedP ? 2048 : 4096;
    softmax_kernel<<<NB * 2048, 256, 0, stream>>>(S, Pdst, pstride);
    // out[b] = P[b] * V[b]
    gemm_bt_kernel<0, false><<<dim3(16, 4, NB), 256, 0, stream>>>(
        Pdst, pstride, (long long)pstride * 2048,
        VT + (size_t)b0 * 1048576, 2048, 1048576LL,
        out + (size_t)b0 * 1048576, 512, 1048576LL, nullptr, 2048);
  }
}

// Round 4
// 292.846 us; speedup vs baseline: 1.5321x; 1.2851x over previous
//
#include <hip/hip_runtime.h>

// WordAttention: B=8, S=2048, D_IN=D_H=512, fp32 in/out.
// R4: everything single-fp16 (11-bit mantissa is enough: logit err ~1.5e-3,
// same as double-bf16 residual, at 1/3 the MFMA work). fp32 accumulate + fp32
// S + fp32 softmax. 6 dispatches: convx, convw, fused QKV-proj (VT direct),
// scores, softmax (P fp16 in place), PV.

typedef __attribute__((ext_vector_type(8))) _Float16 f16x8;
typedef __attribute__((ext_vector_type(4))) float f32x4;

__device__ __forceinline__ unsigned short f2h(float f) {
  _Float16 h = (_Float16)f;
  return *(unsigned short*)&h;
}

__device__ __forceinline__ void load_lds16(const void* g, void* l) {
  __builtin_amdgcn_global_load_lds(
      (const __attribute__((address_space(1))) unsigned int*)g,
      (__attribute__((address_space(3))) unsigned int*)l, 16, 0, 0);
}

// ---- x fp32 -> fp16 ----
__global__ __launch_bounds__(256) void convx_kernel(const float* __restrict__ x,
                                                    unsigned short* __restrict__ xh) {
  int i = blockIdx.x * 256 + threadIdx.x;
  float4 v = ((const float4*)x)[i];
  union { unsigned short h[4]; short4 s4; } u;
  u.h[0] = f2h(v.x); u.h[1] = f2h(v.y); u.h[2] = f2h(v.z); u.h[3] = f2h(v.w);
  ((short4*)xh)[i] = u.s4;
}

// ---- W [d][h] fp32 -> Wt [h][d] fp16; z = 0,1,2 selects Wq/Wk/Wv ----
__global__ __launch_bounds__(256) void convw_kernel(
    const float* __restrict__ W0, const float* __restrict__ W1,
    const float* __restrict__ W2, unsigned short* __restrict__ Wt) {
  const float* W = (blockIdx.z == 0) ? W0 : (blockIdx.z == 1) ? W1 : W2;
  unsigned short* t = Wt + (size_t)blockIdx.z * 512 * 512;
  __shared__ float tile[32][33];
  int tx = threadIdx.x, ty = threadIdx.y;  // 32 x 8
  int h0 = blockIdx.x * 32, d0 = blockIdx.y * 32;
  for (int i = ty; i < 32; i += 8) tile[i][tx] = W[(long)(d0 + i) * 512 + h0 + tx];
  __syncthreads();
  for (int i = ty; i < 32; i += 8)
    t[(long)(h0 + i) * 512 + d0 + tx] = f2h(tile[tx][i]);
}

// ---- 128x128-tile GEMM, C = A * Bt^T (+bias). fp16 in, fp32 acc.
//      OUT_KIND 0: fp32 C.
//      OUT_KIND 1: QKV epilogue — col<1024 -> fp16 QK[row][col] (ldc=1024);
//                  col>=1024  -> fp16 VT[b][col-1024][s] transposed write.
template <int OUT_KIND, bool BIAS>
__global__ __launch_bounds__(256) void gemm_bt_kernel(
    const unsigned short* __restrict__ A, int lda, long long sA,
    const unsigned short* __restrict__ Bt, int ldb, long long sB,
    void* __restrict__ Cout, int ldc, long long sC,
    unsigned short* __restrict__ VTout,
    const float* __restrict__ b0p, const float* __restrict__ b1p,
    const float* __restrict__ b2p, int K) {
  __shared__ alignas(16) unsigned short As[128 * 32];
  __shared__ alignas(16) unsigned short Bs[128 * 32];
  const int t = threadIdx.x;
  const long long bm = (long long)blockIdx.x * 128;
  const long long bn = (long long)blockIdx.y * 128;
  const unsigned short* Ab = A + (long long)blockIdx.z * sA;
  const unsigned short* Bb = Bt + (long long)blockIdx.z * sB;

  const int ar = t >> 2;        // row 0..63 within 64-row staging half
  const int ac = (t & 3) * 8;   // k-col start (16 B)

  f32x4 acc[4][4];
#pragma unroll
  for (int i = 0; i < 4; i++)
#pragma unroll
    for (int j = 0; j < 4; j++) acc[i][j] = {0.f, 0.f, 0.f, 0.f};

  const int lane = t & 63;
  const int wave = t >> 6;
  const int wm = (wave & 1) * 64;
  const int wn = (wave >> 1) * 64;
  const int fm = lane & 15;
  const int k8 = (lane >> 4) * 8;

  for (int kt = 0; kt < K; kt += 32) {
#pragma unroll
    for (int r = 0; r < 2; r++)
      load_lds16(Ab + (bm + r * 64 + ar) * lda + kt + ac, &As[r * 2048 + t * 8]);
#pragma unroll
    for (int r = 0; r < 2; r++)
      load_lds16(Bb + (bn + r * 64 + ar) * ldb + kt + ac, &Bs[r * 2048 + t * 8]);
    __syncthreads();

    f16x8 af[4], bfr[4];
#pragma unroll
    for (int i = 0; i < 4; i++)
      af[i] = *(const f16x8*)&As[(wm + i * 16 + fm) * 32 + k8];
#pragma unroll
    for (int j = 0; j < 4; j++)
      bfr[j] = *(const f16x8*)&Bs[(wn + j * 16 + fm) * 32 + k8];
#pragma unroll
    for (int i = 0; i < 4; i++)
#pragma unroll
      for (int j = 0; j < 4; j++)
        acc[i][j] = __builtin_amdgcn_mfma_f32_16x16x32_f16(af[i], bfr[j], acc[i][j], 0, 0, 0);
    __syncthreads();
  }

  float* Cf = (float*)Cout;
  unsigned short* Ch = (unsigned short*)Cout;
  const long long cz = (long long)blockIdx.z * sC;
  const int crow = (lane >> 4) * 4;  // C/D: col=lane&15, row=(lane>>4)*4+reg
  const int ccol = lane & 15;
#pragma unroll
  for (int j = 0; j < 4; j++) {
    const long long col = bn + wn + j * 16 + ccol;
    float bv = 0.0f;
    if (BIAS)
      bv = (col < 512) ? b0p[col] : (col < 1024) ? b1p[col - 512] : b2p[col - 1024];
#pragma unroll
    for (int i = 0; i < 4; i++) {
      const long long row0 = bm + wm + i * 16 + crow;
      if (OUT_KIND == 1 && col >= 1024) {
        // VT[b][col-1024][s], s = row0..row0+3 consecutive within one batch
        const long long b = row0 >> 11;
        const long long s = row0 & 2047;
        union { unsigned short h[4]; short4 s4; } u;
#pragma unroll
        for (int r = 0; r < 4; r++) u.h[r] = f2h(acc[i][j][r] + bv);
        *(short4*)(VTout + (b * 512 + (col - 1024)) * 2048 + s) = u.s4;
      } else {
#pragma unroll
        for (int r = 0; r < 4; r++) {
          float v = acc[i][j][r] + bv;
          long long idx = cz + (row0 + r) * ldc + col;
          if (OUT_KIND == 1) Ch[idx] = f2h(v);
          else               Cf[idx] = v;
        }
      }
    }
  }
}

// ---- row softmax over 2048 fp32 logits -> fp16 P in place (row head) ----
__global__ __launch_bounds__(256) void softmax_kernel(float* __restrict__ S) {
  float* Srow = S + (long long)blockIdx.x * 2048;
  unsigned short* Prow = (unsigned short*)Srow;  // fp16 row over first half
  const int t = threadIdx.x;
  float4 v0 = ((const float4*)Srow)[t * 2];
  float4 v1 = ((const float4*)Srow)[t * 2 + 1];
  float m = fmaxf(fmaxf(fmaxf(v0.x, v0.y), fmaxf(v0.z, v0.w)),
                  fmaxf(fmaxf(v1.x, v1.y), fmaxf(v1.z, v1.w)));
#pragma unroll
  for (int off = 32; off > 0; off >>= 1) m = fmaxf(m, __shfl_xor(m, off));
  __shared__ float redm[4];
  __shared__ float reds[4];
  const int wave = t >> 6, lane = t & 63;
  if (lane == 0) redm[wave] = m;
  __syncthreads();  // fences all global reads above from the in-place writes below
  m = fmaxf(fmaxf(redm[0], redm[1]), fmaxf(redm[2], redm[3]));
  float e[8];
  e[0] = __expf(v0.x - m); e[1] = __expf(v0.y - m);
  e[2] = __expf(v0.z - m); e[3] = __expf(v0.w - m);
  e[4] = __expf(v1.x - m); e[5] = __expf(v1.y - m);
  e[6] = __expf(v1.z - m); e[7] = __expf(v1.w - m);
  float s = 0.f;
#pragma unroll
  for (int k = 0; k < 8; k++) s += e[k];
#pragma unroll
  for (int off = 32; off > 0; off >>= 1) s += __shfl_xor(s, off);
  if (lane == 0) reds[wave] = s;
  __syncthreads();
  s = reds[0] + reds[1] + reds[2] + reds[3];
  float inv = 1.0f / s;
  union { unsigned short h[8]; int4 v; } u;
#pragma unroll
  for (int k = 0; k < 8; k++) u.h[k] = f2h(e[k] * inv);
  ((int4*)Prow)[t] = u.v;
}

extern "C" void kernel_launch(void* const* d_in, const int* in_sizes, int n_in,
                              void* d_out, int out_size, void* d_ws, size_t ws_size,
                              hipStream_t stream) {
  const float* x  = (const float*)d_in[0];
  const float* Wq = (const float*)d_in[1];
  const float* bq = (const float*)d_in[2];
  const float* Wk = (const float*)d_in[3];
  const float* bk = (const float*)d_in[4];
  const float* Wv = (const float*)d_in[5];
  const float* bv = (const float*)d_in[6];
  float* out = (float*)d_out;

  const size_t SZ = (size_t)16384 * 512 * 2;  // 16.78 MB (fp16 [16384,512])
  const size_t S1 = (size_t)2048 * 2048 * 4;  // one batch of fp32 scores

  char* p = (char*)d_ws;
  unsigned short* xh = (unsigned short*)p; p += SZ;
  unsigned short* Wt = (unsigned short*)p; p += (size_t)3 * 512 * 512 * 2;
  unsigned short* QK = (unsigned short*)p; p += 2 * SZ;  // [16384][1024]: Q|K
  unsigned short* VT = (unsigned short*)p; p += SZ;      // [b][512][2048]
  size_t fixed = (size_t)(p - (char*)d_ws);

  float* S;
  int NB;
  if (ws_size >= fixed + 8 * S1)      { NB = 8; S = (float*)p; }
  else if (ws_size >= fixed + 4 * S1) { NB = 4; S = (float*)p; }
  else if (ws_size >= fixed + 2 * S1) { NB = 2; S = (float*)p; }
  else                                { NB = 1; S = (float*)xh; }  // x dead by then

  // 1) conversions
  convx_kernel<<<8192, 256, 0, stream>>>(x, xh);
  convw_kernel<<<dim3(16, 16, 3), dim3(32, 8), 0, stream>>>(Wq, Wk, Wv, Wt);

  // 2) fused QKV projection: [16384,512] x [512,1536]^T + bias.
  //    cols 0..1023 -> QK; cols 1024..1535 -> VT (transposed in epilogue)
  gemm_bt_kernel<1, true><<<dim3(128, 12, 1), 256, 0, stream>>>(
      xh, 512, 0, Wt, 512, 0, QK, 1024, 0, VT, bq, bk, bv, 512);

  // 3) attention, chunked over batches
  for (int b0 = 0; b0 < 8; b0 += NB) {
    // scores: S[b][q][k] = Q[b] K[b]^T (fp32 out)
    gemm_bt_kernel<0, false><<<dim3(16, 16, NB), 256, 0, stream>>>(
        QK + (size_t)b0 * 2097152, 1024, 2097152LL,
        QK + 512 + (size_t)b0 * 2097152, 1024, 2097152LL,
        S, 2048, 4194304LL, nullptr, nullptr, nullptr, nullptr, 512);
    // softmax rows -> fp16 P in place (row stride 4096 shorts)
    softmax_kernel<<<NB * 2048, 256, 0, stream>>>(S);
    // out[b] = P[b] * V[b]
    gemm_bt_kernel<0, false><<<dim3(16, 4, NB), 256, 0, stream>>>(
        (const unsigned short*)S, 4096, 8388608LL,
        VT + (size_t)b0 * 1048576, 2048, 1048576LL,
        out + (size_t)b0 * 1048576, 512, 1048576LL, nullptr, nullptr, nullptr, nullptr, 2048);
  }
}